// Round 24
// baseline (195.098 us; speedup 1.0000x reference)
//
#include <hip/hip_runtime.h>
#include <math.h>

#define N_NODES 50000
#define D 128
#define NE 800000
#define BN 64                  // nodes per bucket (dst >> 6)
#define NBUCK 782              // ceil(N_NODES / 64)
#define CAP 1280               // records per bucket (mean 1024, 8 sigma)
#define EPB 4096               // edges per partition block
#define PBLK 196               // ceil(NE / EPB)
#define F2B_BLKS 6250          // N*D/4 / 256
#define WPREP_BLKS 384         // 2*12*128*32 / 256
#define MPITCH 68              // uint pitch for LDS mean rows

typedef unsigned int uint;
typedef unsigned short ushort;
typedef unsigned char uchar;

using bf16x8 = __attribute__((ext_vector_type(8))) short;
using f32x4  = __attribute__((ext_vector_type(4))) float;

// ---- bf16 helpers (bit-level, RN-even) ----
__device__ __forceinline__ float bflo(uint w) {
    union { uint u; float f; } c; c.u = w << 16; return c.f;
}
__device__ __forceinline__ float bfhi(uint w) {
    union { uint u; float f; } c; c.u = w & 0xffff0000u; return c.f;
}
__device__ __forceinline__ uint fp2bf_rn(float f) {
    union { float f; uint u; } c; c.f = f;
    return (c.u + 0x7fffu + ((c.u >> 16) & 1u)) >> 16;
}

// ---------------------------------------------------------------------------
// build: [0, 2*PBLK) edge partition into 64-node bucket record runs;
//        then x -> bf16 + fp8; then W pre-pack.
// rec = src | (dst&63)<<17.  After this kernel bcur[b] = bucket record count.
// ---------------------------------------------------------------------------
__global__ __launch_bounds__(256) void build_kernel(
    const float4* __restrict__ x4, uint2* __restrict__ featb2,
    uint* __restrict__ feat8w,
    const float* __restrict__ Wl, const float* __restrict__ Wr,
    ushort* __restrict__ Wpack,
    const int* __restrict__ srcA, const int* __restrict__ dstA,
    const int* __restrict__ srcB, const int* __restrict__ dstB,
    int* __restrict__ bcurA, int* __restrict__ bcurB,
    uint* __restrict__ ebufA, uint* __restrict__ ebufB) {
    const int blk = blockIdx.x;
    const int t   = threadIdx.x;
    if (blk < 2 * PBLK) {
        __shared__ int h[NBUCK];
        __shared__ int base[NBUCK];
        const int typ = blk >= PBLK;
        const int* src = typ ? srcB : srcA;
        const int* dst = typ ? dstB : dstA;
        int* bc        = typ ? bcurB : bcurA;
        uint* ebuf     = typ ? ebufB : ebufA;
        const int e0 = (blk - (typ ? PBLK : 0)) * EPB;
        for (int j = t; j < NBUCK; j += 256) h[j] = 0;
        __syncthreads();
#pragma unroll
        for (int i = 0; i < EPB / 256; ++i) {
            const int e = e0 + t + i * 256;
            if (e < NE) atomicAdd(&h[dst[e] >> 6], 1);
        }
        __syncthreads();
        for (int j = t; j < NBUCK; j += 256) {
            const int c = h[j];
            base[j] = c ? atomicAdd(&bc[j], c) : 0;
            h[j] = 0;                    // reuse as local cursor
        }
        __syncthreads();
#pragma unroll
        for (int i = 0; i < EPB / 256; ++i) {
            const int e = e0 + t + i * 256;
            if (e < NE) {
                const int d  = dst[e];
                const int bk = d >> 6;
                const int pos = atomicAdd(&h[bk], 1);
                const int off = base[bk] + pos;
                if (off < CAP)
                    ebuf[(size_t)bk * CAP + off] = (uint)src[e] | ((uint)(d & 63) << 17);
            }
        }
    } else if (blk < 2 * PBLK + F2B_BLKS) {
        const int i = (blk - 2 * PBLK) * 256 + t;
        float4 v = x4[i];
        uint2 o;
        o.x = fp2bf_rn(v.x) | (fp2bf_rn(v.y) << 16);
        o.y = fp2bf_rn(v.z) | (fp2bf_rn(v.w) << 16);
        featb2[i] = o;
        int pk = __builtin_amdgcn_cvt_pk_fp8_f32(v.x, v.y, 0, false);
        pk = __builtin_amdgcn_cvt_pk_fp8_f32(v.z, v.w, pk, true);
        feat8w[i] = (uint)pk;
    } else {
        const int i   = (blk - 2 * PBLK - F2B_BLKS) * 256 + t;  // [2][12][128][32]
        const int l   = i / 49152;
        const int rem = i % 49152;
        const int ks  = rem / 4096;
        const int n   = (rem % 4096) / 32;
        const int kk  = rem % 32;
        const int r   = ks * 32 + kk;
        float v;
        if (r < 128)       v = Wl[(((size_t)l * 2 + 0) * 128 + r) * 128 + n];
        else if (r < 256)  v = Wl[(((size_t)l * 2 + 1) * 128 + (r - 128)) * 128 + n];
        else               v = Wr[(((size_t)l * 2 + 0) * 128 + (r - 256)) * 128 + n]
                             + Wr[(((size_t)l * 2 + 1) * 128 + (r - 256)) * 128 + n];
        Wpack[i] = (ushort)fp2bf_rn(v);
    }
}

// ---------------------------------------------------------------------------
// fused: one block per 64-node bucket.
// sort=1 (layer 0): stage ebuf records into (reused) means-LDS, count/scan/
//   place into per-node lists + counting-rank all 128 lists; save lists+meta
//   to global for layer 1.  meta = beg | deg<<11 | slot<<22.
// sort=0 (layer 1): stage saved lists + meta from global.
// Then: gather (128 clusters x 8 lanes, uint4 fp8 rows, unroll-4 immediate
// accumulation; __launch_bounds__(1024,4) gives 128-VGPR headroom so the
// deeper unroll does NOT spill) -> bf16 means in LDS -> 64x128 MFMA GEMM.
//   out[i,:] = act( meanA@W0 + meanB@W1 + self@(Wr0+Wr1) + b0+b1 )
// ---------------------------------------------------------------------------
__global__ __launch_bounds__(1024, 4) void fused_kernel(
    const uint4* __restrict__ feat,      // layer input bf16 [N][16] (self/GEMM)
    const uint4* __restrict__ feat8,     // layer input fp8 [N][8]  (gather)
    const uint* __restrict__ ebufA, const uint* __restrict__ ebufB,
    const int* __restrict__ bcntA, const int* __restrict__ bcntB,
    uint* __restrict__ glidx,            // [NBUCK][2][CAP/2] uints (saved lists)
    uint* __restrict__ gmeta,            // [NBUCK][128] packed meta
    const ushort* __restrict__ Wpack,    // [12][128][32] bf16 for this layer
    const float* __restrict__ bias0, const float* __restrict__ bias1,
    float* __restrict__ outf, ushort* __restrict__ outb,
    uchar* __restrict__ out8, int sort, int act) {

    __shared__ uint   mlds[2 * BN * MPITCH];   // bf16 means (34816 B); doubles
                                               // as record staging during sort
    __shared__ ushort slidx[2][CAP];           // per-node src lists (5120 B)
    __shared__ uint   lmeta[128];
    __shared__ int    cnt[128], ex[128], cur[128];

    const int b = blockIdx.x;
    const int t = threadIdx.x;
    uint* gl = glidx + (size_t)b * CAP;        // CAP uints = 2*CAP ushorts

    if (sort) {
        // ---- stage records into mlds (A at [0,CAP), B at [CAP,2CAP)) ----
        if (t < 128) cnt[t] = 0;
        int countA = bcntA[b]; if (countA > CAP) countA = CAP;
        int countB = bcntB[b]; if (countB > CAP) countB = CAP;
        const uint* ebA = ebufA + (size_t)b * CAP;
        const uint* ebB = ebufB + (size_t)b * CAP;
        for (int e = t; e < countA; e += 1024) mlds[e] = ebA[e];
        for (int e = t; e < countB; e += 1024) mlds[CAP + e] = ebB[e];
        __syncthreads();
        for (int e = t; e < countA; e += 1024) atomicAdd(&cnt[mlds[e] >> 17], 1);
        for (int e = t; e < countB; e += 1024) atomicAdd(&cnt[64 + (mlds[CAP + e] >> 17)], 1);
        __syncthreads();
        if (t < 128) ex[t] = cnt[t];
        __syncthreads();
        // two independent 64-wide scans (t 0-63 and 64-127)
        for (int off = 1; off < 64; off <<= 1) {
            int v = 0;
            if (t < 128 && (t & 63) >= off) v = ex[t - off];
            __syncthreads();
            if (t < 128 && (t & 63) >= off) ex[t] += v;
            __syncthreads();
        }
        if (t < 128) {
            ex[t] -= cnt[t];               // exclusive
            cur[t] = ex[t];
            // counting rank over all 128 lists (desc, tie by index)
            const int li = cnt[t];
            int r = 0;
#pragma unroll 8
            for (int j = 0; j < 128; ++j) {
                const int lj = cnt[j];
                r += (lj > li) || (lj == li && j < t);
            }
            const uint m = (uint)ex[t] | ((uint)cnt[t] << 11) | ((uint)t << 22);
            lmeta[r] = m;
            gmeta[b * 128 + r] = m;
        }
        __syncthreads();
        for (int e = t; e < countA; e += 1024) {
            const uint rec = mlds[e];
            const int p = atomicAdd(&cur[rec >> 17], 1);
            slidx[0][p] = (ushort)(rec & 0x1FFFFu);
        }
        for (int e = t; e < countB; e += 1024) {
            const uint rec = mlds[CAP + e];
            const int p = atomicAdd(&cur[64 + (rec >> 17)], 1);
            slidx[1][p] = (ushort)(rec & 0x1FFFFu);
        }
        __syncthreads();
        // ---- save lists for layer 1 (coalesced uint copies) ----
        {
            const uint* sA = (const uint*)slidx[0];
            const uint* sB = (const uint*)slidx[1];
            for (int i = t; i < CAP / 2; i += 1024) gl[i] = sA[i];
            for (int i = t; i < CAP / 2; i += 1024) gl[CAP / 2 + i] = sB[i];
        }
    } else {
        // ---- stage saved lists + meta ----
        uint* sA = (uint*)slidx[0];
        uint* sB = (uint*)slidx[1];
        for (int i = t; i < CAP / 2; i += 1024) sA[i] = gl[i];
        for (int i = t; i < CAP / 2; i += 1024) sB[i] = gl[CAP / 2 + i];
        if (t < 128) lmeta[t] = gmeta[b * 128 + t];
        __syncthreads();
    }

    // ---- gather: 128 clusters x 8 lanes, uint4 fp8 rows, unroll 4 ----
    const int j = t >> 3, ln = t & 7;
    {
        const uint m = lmeta[j];
        const int beg = (int)(m & 0x7FFu);
        const int deg = (int)((m >> 11) & 0x7FFu);
        const int slot = (int)(m >> 22);
        const int typ = slot >> 6, lnode = slot & 63;
        const ushort* lx = slidx[typ] + beg;
        float a[16] = {0.f,0.f,0.f,0.f,0.f,0.f,0.f,0.f,
                       0.f,0.f,0.f,0.f,0.f,0.f,0.f,0.f};
#define ACC16(vv) { \
    auto q0 = __builtin_amdgcn_cvt_pk_f32_fp8((int)(vv).x, false); \
    auto q1 = __builtin_amdgcn_cvt_pk_f32_fp8((int)(vv).x, true);  \
    a[0]+=q0[0];  a[1]+=q0[1];  a[2]+=q1[0];  a[3]+=q1[1];         \
    auto q2 = __builtin_amdgcn_cvt_pk_f32_fp8((int)(vv).y, false); \
    auto q3 = __builtin_amdgcn_cvt_pk_f32_fp8((int)(vv).y, true);  \
    a[4]+=q2[0];  a[5]+=q2[1];  a[6]+=q3[0];  a[7]+=q3[1];         \
    auto q4 = __builtin_amdgcn_cvt_pk_f32_fp8((int)(vv).z, false); \
    auto q5 = __builtin_amdgcn_cvt_pk_f32_fp8((int)(vv).z, true);  \
    a[8]+=q4[0];  a[9]+=q4[1];  a[10]+=q5[0]; a[11]+=q5[1];        \
    auto q6 = __builtin_amdgcn_cvt_pk_f32_fp8((int)(vv).w, false); \
    auto q7 = __builtin_amdgcn_cvt_pk_f32_fp8((int)(vv).w, true);  \
    a[12]+=q6[0]; a[13]+=q6[1]; a[14]+=q7[0]; a[15]+=q7[1]; }
        int e = 0;
        for (; e + 4 <= deg; e += 4) {
            uint4 w0 = feat8[(size_t)lx[e]     * 8 + ln];
            uint4 w1 = feat8[(size_t)lx[e + 1] * 8 + ln];
            uint4 w2 = feat8[(size_t)lx[e + 2] * 8 + ln];
            uint4 w3 = feat8[(size_t)lx[e + 3] * 8 + ln];
            ACC16(w0); ACC16(w1); ACC16(w2); ACC16(w3);
        }
        for (; e < deg; ++e) {
            uint4 w0 = feat8[(size_t)lx[e] * 8 + ln];
            ACC16(w0);
        }
#undef ACC16
        if (sort) __syncthreads();       // records in mlds fully consumed
        const float invd = 1.0f / fmaxf((float)deg, 1.0f);
        uint4 o0, o1;
        o0.x = fp2bf_rn(a[0] * invd)  | (fp2bf_rn(a[1] * invd)  << 16);
        o0.y = fp2bf_rn(a[2] * invd)  | (fp2bf_rn(a[3] * invd)  << 16);
        o0.z = fp2bf_rn(a[4] * invd)  | (fp2bf_rn(a[5] * invd)  << 16);
        o0.w = fp2bf_rn(a[6] * invd)  | (fp2bf_rn(a[7] * invd)  << 16);
        o1.x = fp2bf_rn(a[8] * invd)  | (fp2bf_rn(a[9] * invd)  << 16);
        o1.y = fp2bf_rn(a[10] * invd) | (fp2bf_rn(a[11] * invd) << 16);
        o1.z = fp2bf_rn(a[12] * invd) | (fp2bf_rn(a[13] * invd) << 16);
        o1.w = fp2bf_rn(a[14] * invd) | (fp2bf_rn(a[15] * invd) << 16);
        uint4* mp = reinterpret_cast<uint4*>(&mlds[(typ * BN + lnode) * MPITCH + ln * 8]);
        mp[0] = o0;
        mp[1] = o1;
    }
    __syncthreads();

    // ---- GEMM phase: 64 rows x 128 cols, K = 12 x 32, 16 waves ----
    const int wid = t >> 6, wl = t & 63;
    const int mrow = wl & 15, g = wl >> 4;
    const int mt   = wid >> 2;             // 0..3
    const int ntp  = (wid & 3) * 2;        // 0,2,4,6
    const int arow = mt * 16 + mrow;       // 0..63

    f32x4 acc0 = (f32x4){0.f, 0.f, 0.f, 0.f};
    f32x4 acc1 = (f32x4){0.f, 0.f, 0.f, 0.f};
#pragma unroll
    for (int ks = 0; ks < 12; ++ks) {
        union { uint4 u; bf16x8 v; } av;
        if (ks < 8) {
            av.u = *reinterpret_cast<const uint4*>(
                &mlds[((ks >> 2) * BN + arow) * MPITCH + (ks & 3) * 16 + g * 4]);
        } else {
            int srow = b * BN + arow;
            if (srow >= N_NODES) srow = N_NODES - 1;
            av.u = feat[(size_t)srow * 16 + (ks & 3) * 4 + g];
        }
        const ushort* Wk = Wpack + (size_t)ks * 128 * 32;
        union { uint4 u; bf16x8 v; } bv0, bv1;
        bv0.u = *reinterpret_cast<const uint4*>(Wk + ((ntp * 16 + mrow) * 32 + g * 8));
        bv1.u = *reinterpret_cast<const uint4*>(Wk + (((ntp + 1) * 16 + mrow) * 32 + g * 8));
        acc0 = __builtin_amdgcn_mfma_f32_16x16x32_bf16(av.v, bv0.v, acc0, 0, 0, 0);
        acc1 = __builtin_amdgcn_mfma_f32_16x16x32_bf16(av.v, bv1.v, acc1, 0, 0, 0);
    }

    // ---- epilogue ----
#pragma unroll
    for (int q = 0; q < 2; ++q) {
        const f32x4 av = q ? acc1 : acc0;
        const int col = (ntp + q) * 16 + mrow;
        const float bias = bias0[col] + bias1[col];
#pragma unroll
        for (int r = 0; r < 4; ++r) {
            const int row = b * BN + mt * 16 + g * 4 + r;
            if (row < N_NODES) {
                const float v = av[r] + bias;
                if (act) {
                    outf[(size_t)row * D + col] = 1.0f / (1.0f + expf(-v));
                } else {
                    outb[(size_t)row * D + col] = (ushort)fp2bf_rn(v);
                    const int pk = __builtin_amdgcn_cvt_pk_fp8_f32(v, v, 0, false);
                    out8[(size_t)row * D + col] = (uchar)(pk & 0xFF);
                }
            }
        }
    }
}

// ---------------------------------------------------------------------------
extern "C" void kernel_launch(void* const* d_in, const int* in_sizes, int n_in,
                              void* d_out, int out_size, void* d_ws, size_t ws_size,
                              hipStream_t stream) {
    const float* x    = (const float*)d_in[0];
    const int*   ei_a = (const int*)d_in[2];
    const int*   ei_b = (const int*)d_in[3];
    const float* Wl   = (const float*)d_in[4];
    const float* bl   = (const float*)d_in[5];
    const float* Wr   = (const float*)d_in[6];
    float* out = (float*)d_out;

    // ---- workspace (~51.0 MB) ----
    ushort* featb = (ushort*)d_ws;                           // [N][128] bf16
    ushort* feat2 = featb + (size_t)N_NODES * D;             // [N][128] bf16
    uchar* feat8  = (uchar*)(feat2 + (size_t)N_NODES * D);   // [N][128] fp8
    uchar* feat28 = feat8 + (size_t)N_NODES * D;             // [N][128] fp8
    uint* ebufA = (uint*)(feat28 + (size_t)N_NODES * D);     // NBUCK*CAP
    uint* ebufB = ebufA + (size_t)NBUCK * CAP;
    uint* glidx = ebufB + (size_t)NBUCK * CAP;               // NBUCK*CAP uints
    uint* gmeta = glidx + (size_t)NBUCK * CAP;               // NBUCK*128
    int* bcurA  = (int*)(gmeta + (size_t)NBUCK * 128);       // NBUCK
    int* bcurB  = bcurA + NBUCK;
    ushort* Wpack = (ushort*)(((size_t)(bcurB + NBUCK) + 63) & ~(size_t)63);

    const int* srcA = ei_a;
    const int* dstA = ei_a + NE;
    const int* srcB = ei_b;
    const int* dstB = ei_b + NE;

    hipMemsetAsync(bcurA, 0, 2ull * NBUCK * sizeof(int), stream);
    build_kernel<<<2 * PBLK + F2B_BLKS + WPREP_BLKS, 256, 0, stream>>>(
        (const float4*)x, (uint2*)featb, (uint*)feat8, Wl, Wr, Wpack,
        srcA, dstA, srcB, dstB, bcurA, bcurB, ebufA, ebufB);

    fused_kernel<<<NBUCK, 1024, 0, stream>>>(
        (const uint4*)featb, (const uint4*)feat8, ebufA, ebufB, bcurA, bcurB,
        glidx, gmeta, Wpack, bl + 0 * D, bl + 1 * D,
        nullptr, feat2, feat28, 1, 0);
    fused_kernel<<<NBUCK, 1024, 0, stream>>>(
        (const uint4*)feat2, (const uint4*)feat28, ebufA, ebufB, bcurA, bcurB,
        glidx, gmeta, Wpack + (size_t)12 * 128 * 32, bl + 2 * D, bl + 3 * D,
        out, nullptr, nullptr, 0, 1);
}

// Round 25
// 163.218 us; speedup vs baseline: 1.1953x; 1.1953x over previous
//
#include <hip/hip_runtime.h>
#include <math.h>

#define N_NODES 50000
#define D 128
#define NE 800000
#define BN 64                  // nodes per bucket (dst >> 6)
#define NBUCK 782              // ceil(N_NODES / 64)
#define CAP 1280               // records per bucket (mean 1024, 8 sigma)
#define EPB 4096               // edges per partition block
#define PBLK 196               // ceil(NE / EPB)
#define F2B_BLKS 6250          // N*D/4 / 256
#define WPREP_BLKS 384         // 2*12*128*32 / 256
#define MPITCH 68              // uint pitch for LDS mean rows

typedef unsigned int uint;
typedef unsigned short ushort;
typedef unsigned char uchar;

using bf16x8 = __attribute__((ext_vector_type(8))) short;
using f32x4  = __attribute__((ext_vector_type(4))) float;

// ---- bf16 helpers (bit-level, RN-even) ----
__device__ __forceinline__ float bflo(uint w) {
    union { uint u; float f; } c; c.u = w << 16; return c.f;
}
__device__ __forceinline__ float bfhi(uint w) {
    union { uint u; float f; } c; c.u = w & 0xffff0000u; return c.f;
}
__device__ __forceinline__ uint fp2bf_rn(float f) {
    union { float f; uint u; } c; c.f = f;
    return (c.u + 0x7fffu + ((c.u >> 16) & 1u)) >> 16;
}

// ---------------------------------------------------------------------------
// build: [0, 2*PBLK) edge partition into 64-node bucket record runs;
//        then x -> bf16 + fp8; then W pre-pack.
// rec = src | (dst&63)<<17.  After this kernel bcur[b] = bucket record count.
// ---------------------------------------------------------------------------
__global__ __launch_bounds__(256) void build_kernel(
    const float4* __restrict__ x4, uint2* __restrict__ featb2,
    uint* __restrict__ feat8w,
    const float* __restrict__ Wl, const float* __restrict__ Wr,
    ushort* __restrict__ Wpack,
    const int* __restrict__ srcA, const int* __restrict__ dstA,
    const int* __restrict__ srcB, const int* __restrict__ dstB,
    int* __restrict__ bcurA, int* __restrict__ bcurB,
    uint* __restrict__ ebufA, uint* __restrict__ ebufB) {
    const int blk = blockIdx.x;
    const int t   = threadIdx.x;
    if (blk < 2 * PBLK) {
        __shared__ int h[NBUCK];
        __shared__ int base[NBUCK];
        const int typ = blk >= PBLK;
        const int* src = typ ? srcB : srcA;
        const int* dst = typ ? dstB : dstA;
        int* bc        = typ ? bcurB : bcurA;
        uint* ebuf     = typ ? ebufB : ebufA;
        const int e0 = (blk - (typ ? PBLK : 0)) * EPB;
        for (int j = t; j < NBUCK; j += 256) h[j] = 0;
        __syncthreads();
#pragma unroll
        for (int i = 0; i < EPB / 256; ++i) {
            const int e = e0 + t + i * 256;
            if (e < NE) atomicAdd(&h[dst[e] >> 6], 1);
        }
        __syncthreads();
        for (int j = t; j < NBUCK; j += 256) {
            const int c = h[j];
            base[j] = c ? atomicAdd(&bc[j], c) : 0;
            h[j] = 0;                    // reuse as local cursor
        }
        __syncthreads();
#pragma unroll
        for (int i = 0; i < EPB / 256; ++i) {
            const int e = e0 + t + i * 256;
            if (e < NE) {
                const int d  = dst[e];
                const int bk = d >> 6;
                const int pos = atomicAdd(&h[bk], 1);
                const int off = base[bk] + pos;
                if (off < CAP)
                    ebuf[(size_t)bk * CAP + off] = (uint)src[e] | ((uint)(d & 63) << 17);
            }
        }
    } else if (blk < 2 * PBLK + F2B_BLKS) {
        const int i = (blk - 2 * PBLK) * 256 + t;
        float4 v = x4[i];
        uint2 o;
        o.x = fp2bf_rn(v.x) | (fp2bf_rn(v.y) << 16);
        o.y = fp2bf_rn(v.z) | (fp2bf_rn(v.w) << 16);
        featb2[i] = o;
        int pk = __builtin_amdgcn_cvt_pk_fp8_f32(v.x, v.y, 0, false);
        pk = __builtin_amdgcn_cvt_pk_fp8_f32(v.z, v.w, pk, true);
        feat8w[i] = (uint)pk;
    } else {
        const int i   = (blk - 2 * PBLK - F2B_BLKS) * 256 + t;  // [2][12][128][32]
        const int l   = i / 49152;
        const int rem = i % 49152;
        const int ks  = rem / 4096;
        const int n   = (rem % 4096) / 32;
        const int kk  = rem % 32;
        const int r   = ks * 32 + kk;
        float v;
        if (r < 128)       v = Wl[(((size_t)l * 2 + 0) * 128 + r) * 128 + n];
        else if (r < 256)  v = Wl[(((size_t)l * 2 + 1) * 128 + (r - 128)) * 128 + n];
        else               v = Wr[(((size_t)l * 2 + 0) * 128 + (r - 256)) * 128 + n]
                             + Wr[(((size_t)l * 2 + 1) * 128 + (r - 256)) * 128 + n];
        Wpack[i] = (ushort)fp2bf_rn(v);
    }
}

// ---------------------------------------------------------------------------
// fused: one block per 64-node bucket.
// sort=1 (layer 0): stage ebuf records into (reused) means-LDS, count/scan/
//   place into per-node lists + counting-rank all 128 lists; save lists+meta
//   to global for layer 1.  meta = beg | deg<<11 | slot<<22.
// sort=0 (layer 1): stage saved lists + meta from global.
// Then: gather (128 clusters x 8 lanes, uint4 fp8 rows, unroll-2 immediate
// accumulation — the no-spill ceiling at 32 VGPR / 2 blocks/CU, which beats
// every deeper-ILP variant tried) -> bf16 means in LDS -> 64x128 MFMA GEMM.
//   out[i,:] = act( meanA@W0 + meanB@W1 + self@(Wr0+Wr1) + b0+b1 )
// ---------------------------------------------------------------------------
__global__ __launch_bounds__(1024, 8) void fused_kernel(
    const uint4* __restrict__ feat,      // layer input bf16 [N][16] (self/GEMM)
    const uint4* __restrict__ feat8,     // layer input fp8 [N][8]  (gather)
    const uint* __restrict__ ebufA, const uint* __restrict__ ebufB,
    const int* __restrict__ bcntA, const int* __restrict__ bcntB,
    uint* __restrict__ glidx,            // [NBUCK][2][CAP/2] uints (saved lists)
    uint* __restrict__ gmeta,            // [NBUCK][128] packed meta
    const ushort* __restrict__ Wpack,    // [12][128][32] bf16 for this layer
    const float* __restrict__ bias0, const float* __restrict__ bias1,
    float* __restrict__ outf, ushort* __restrict__ outb,
    uchar* __restrict__ out8, int sort, int act) {

    __shared__ uint   mlds[2 * BN * MPITCH];   // bf16 means (34816 B); doubles
                                               // as record staging during sort
    __shared__ ushort slidx[2][CAP];           // per-node src lists (5120 B)
    __shared__ uint   lmeta[128];
    __shared__ int    cnt[128], ex[128], cur[128];

    const int b = blockIdx.x;
    const int t = threadIdx.x;
    uint* gl = glidx + (size_t)b * CAP;        // CAP uints = 2*CAP ushorts

    if (sort) {
        // ---- stage records into mlds (A at [0,CAP), B at [CAP,2CAP)) ----
        if (t < 128) cnt[t] = 0;
        int countA = bcntA[b]; if (countA > CAP) countA = CAP;
        int countB = bcntB[b]; if (countB > CAP) countB = CAP;
        const uint* ebA = ebufA + (size_t)b * CAP;
        const uint* ebB = ebufB + (size_t)b * CAP;
        for (int e = t; e < countA; e += 1024) mlds[e] = ebA[e];
        for (int e = t; e < countB; e += 1024) mlds[CAP + e] = ebB[e];
        __syncthreads();
        for (int e = t; e < countA; e += 1024) atomicAdd(&cnt[mlds[e] >> 17], 1);
        for (int e = t; e < countB; e += 1024) atomicAdd(&cnt[64 + (mlds[CAP + e] >> 17)], 1);
        __syncthreads();
        if (t < 128) ex[t] = cnt[t];
        __syncthreads();
        // two independent 64-wide scans (t 0-63 and 64-127)
        for (int off = 1; off < 64; off <<= 1) {
            int v = 0;
            if (t < 128 && (t & 63) >= off) v = ex[t - off];
            __syncthreads();
            if (t < 128 && (t & 63) >= off) ex[t] += v;
            __syncthreads();
        }
        if (t < 128) {
            ex[t] -= cnt[t];               // exclusive
            cur[t] = ex[t];
            // counting rank over all 128 lists (desc, tie by index)
            const int li = cnt[t];
            int r = 0;
#pragma unroll 8
            for (int j = 0; j < 128; ++j) {
                const int lj = cnt[j];
                r += (lj > li) || (lj == li && j < t);
            }
            const uint m = (uint)ex[t] | ((uint)cnt[t] << 11) | ((uint)t << 22);
            lmeta[r] = m;
            gmeta[b * 128 + r] = m;
        }
        __syncthreads();
        for (int e = t; e < countA; e += 1024) {
            const uint rec = mlds[e];
            const int p = atomicAdd(&cur[rec >> 17], 1);
            slidx[0][p] = (ushort)(rec & 0x1FFFFu);
        }
        for (int e = t; e < countB; e += 1024) {
            const uint rec = mlds[CAP + e];
            const int p = atomicAdd(&cur[64 + (rec >> 17)], 1);
            slidx[1][p] = (ushort)(rec & 0x1FFFFu);
        }
        __syncthreads();
        // ---- save lists for layer 1 (coalesced uint copies) ----
        {
            const uint* sA = (const uint*)slidx[0];
            const uint* sB = (const uint*)slidx[1];
            for (int i = t; i < CAP / 2; i += 1024) gl[i] = sA[i];
            for (int i = t; i < CAP / 2; i += 1024) gl[CAP / 2 + i] = sB[i];
        }
    } else {
        // ---- stage saved lists + meta ----
        uint* sA = (uint*)slidx[0];
        uint* sB = (uint*)slidx[1];
        for (int i = t; i < CAP / 2; i += 1024) sA[i] = gl[i];
        for (int i = t; i < CAP / 2; i += 1024) sB[i] = gl[CAP / 2 + i];
        if (t < 128) lmeta[t] = gmeta[b * 128 + t];
        __syncthreads();
    }

    // ---- gather: 128 clusters x 8 lanes, uint4 fp8 rows, unroll 2 ----
    const int j = t >> 3, ln = t & 7;
    {
        const uint m = lmeta[j];
        const int beg = (int)(m & 0x7FFu);
        const int deg = (int)((m >> 11) & 0x7FFu);
        const int slot = (int)(m >> 22);
        const int typ = slot >> 6, lnode = slot & 63;
        const ushort* lx = slidx[typ] + beg;
        float a[16] = {0.f,0.f,0.f,0.f,0.f,0.f,0.f,0.f,
                       0.f,0.f,0.f,0.f,0.f,0.f,0.f,0.f};
#define ACC16(vv) { \
    auto q0 = __builtin_amdgcn_cvt_pk_f32_fp8((int)(vv).x, false); \
    auto q1 = __builtin_amdgcn_cvt_pk_f32_fp8((int)(vv).x, true);  \
    a[0]+=q0[0];  a[1]+=q0[1];  a[2]+=q1[0];  a[3]+=q1[1];         \
    auto q2 = __builtin_amdgcn_cvt_pk_f32_fp8((int)(vv).y, false); \
    auto q3 = __builtin_amdgcn_cvt_pk_f32_fp8((int)(vv).y, true);  \
    a[4]+=q2[0];  a[5]+=q2[1];  a[6]+=q3[0];  a[7]+=q3[1];         \
    auto q4 = __builtin_amdgcn_cvt_pk_f32_fp8((int)(vv).z, false); \
    auto q5 = __builtin_amdgcn_cvt_pk_f32_fp8((int)(vv).z, true);  \
    a[8]+=q4[0];  a[9]+=q4[1];  a[10]+=q5[0]; a[11]+=q5[1];        \
    auto q6 = __builtin_amdgcn_cvt_pk_f32_fp8((int)(vv).w, false); \
    auto q7 = __builtin_amdgcn_cvt_pk_f32_fp8((int)(vv).w, true);  \
    a[12]+=q6[0]; a[13]+=q6[1]; a[14]+=q7[0]; a[15]+=q7[1]; }
        int e = 0;
        for (; e + 2 <= deg; e += 2) {
            uint4 w0 = feat8[(size_t)lx[e]     * 8 + ln];
            uint4 w1 = feat8[(size_t)lx[e + 1] * 8 + ln];
            ACC16(w0);
            ACC16(w1);
        }
        if (e < deg) {
            uint4 w0 = feat8[(size_t)lx[e] * 8 + ln];
            ACC16(w0);
        }
#undef ACC16
        __syncthreads();                 // records (sort path) fully consumed
        const float invd = 1.0f / fmaxf((float)deg, 1.0f);
        uint4 o0, o1;
        o0.x = fp2bf_rn(a[0] * invd)  | (fp2bf_rn(a[1] * invd)  << 16);
        o0.y = fp2bf_rn(a[2] * invd)  | (fp2bf_rn(a[3] * invd)  << 16);
        o0.z = fp2bf_rn(a[4] * invd)  | (fp2bf_rn(a[5] * invd)  << 16);
        o0.w = fp2bf_rn(a[6] * invd)  | (fp2bf_rn(a[7] * invd)  << 16);
        o1.x = fp2bf_rn(a[8] * invd)  | (fp2bf_rn(a[9] * invd)  << 16);
        o1.y = fp2bf_rn(a[10] * invd) | (fp2bf_rn(a[11] * invd) << 16);
        o1.z = fp2bf_rn(a[12] * invd) | (fp2bf_rn(a[13] * invd) << 16);
        o1.w = fp2bf_rn(a[14] * invd) | (fp2bf_rn(a[15] * invd) << 16);
        uint4* mp = reinterpret_cast<uint4*>(&mlds[(typ * BN + lnode) * MPITCH + ln * 8]);
        mp[0] = o0;
        mp[1] = o1;
    }
    __syncthreads();

    // ---- GEMM phase: 64 rows x 128 cols, K = 12 x 32, 16 waves ----
    const int wid = t >> 6, wl = t & 63;
    const int mrow = wl & 15, g = wl >> 4;
    const int mt   = wid >> 2;             // 0..3
    const int ntp  = (wid & 3) * 2;        // 0,2,4,6
    const int arow = mt * 16 + mrow;       // 0..63

    f32x4 acc0 = (f32x4){0.f, 0.f, 0.f, 0.f};
    f32x4 acc1 = (f32x4){0.f, 0.f, 0.f, 0.f};
#pragma unroll
    for (int ks = 0; ks < 12; ++ks) {
        union { uint4 u; bf16x8 v; } av;
        if (ks < 8) {
            av.u = *reinterpret_cast<const uint4*>(
                &mlds[((ks >> 2) * BN + arow) * MPITCH + (ks & 3) * 16 + g * 4]);
        } else {
            int srow = b * BN + arow;
            if (srow >= N_NODES) srow = N_NODES - 1;
            av.u = feat[(size_t)srow * 16 + (ks & 3) * 4 + g];
        }
        const ushort* Wk = Wpack + (size_t)ks * 128 * 32;
        union { uint4 u; bf16x8 v; } bv0, bv1;
        bv0.u = *reinterpret_cast<const uint4*>(Wk + ((ntp * 16 + mrow) * 32 + g * 8));
        bv1.u = *reinterpret_cast<const uint4*>(Wk + (((ntp + 1) * 16 + mrow) * 32 + g * 8));
        acc0 = __builtin_amdgcn_mfma_f32_16x16x32_bf16(av.v, bv0.v, acc0, 0, 0, 0);
        acc1 = __builtin_amdgcn_mfma_f32_16x16x32_bf16(av.v, bv1.v, acc1, 0, 0, 0);
    }

    // ---- epilogue ----
#pragma unroll
    for (int q = 0; q < 2; ++q) {
        const f32x4 av = q ? acc1 : acc0;
        const int col = (ntp + q) * 16 + mrow;
        const float bias = bias0[col] + bias1[col];
#pragma unroll
        for (int r = 0; r < 4; ++r) {
            const int row = b * BN + mt * 16 + g * 4 + r;
            if (row < N_NODES) {
                const float v = av[r] + bias;
                if (act) {
                    outf[(size_t)row * D + col] = 1.0f / (1.0f + expf(-v));
                } else {
                    outb[(size_t)row * D + col] = (ushort)fp2bf_rn(v);
                    const int pk = __builtin_amdgcn_cvt_pk_fp8_f32(v, v, 0, false);
                    out8[(size_t)row * D + col] = (uchar)(pk & 0xFF);
                }
            }
        }
    }
}

// ---------------------------------------------------------------------------
extern "C" void kernel_launch(void* const* d_in, const int* in_sizes, int n_in,
                              void* d_out, int out_size, void* d_ws, size_t ws_size,
                              hipStream_t stream) {
    const float* x    = (const float*)d_in[0];
    const int*   ei_a = (const int*)d_in[2];
    const int*   ei_b = (const int*)d_in[3];
    const float* Wl   = (const float*)d_in[4];
    const float* bl   = (const float*)d_in[5];
    const float* Wr   = (const float*)d_in[6];
    float* out = (float*)d_out;

    // ---- workspace (~51.0 MB) ----
    ushort* featb = (ushort*)d_ws;                           // [N][128] bf16
    ushort* feat2 = featb + (size_t)N_NODES * D;             // [N][128] bf16
    uchar* feat8  = (uchar*)(feat2 + (size_t)N_NODES * D);   // [N][128] fp8
    uchar* feat28 = feat8 + (size_t)N_NODES * D;             // [N][128] fp8
    uint* ebufA = (uint*)(feat28 + (size_t)N_NODES * D);     // NBUCK*CAP
    uint* ebufB = ebufA + (size_t)NBUCK * CAP;
    uint* glidx = ebufB + (size_t)NBUCK * CAP;               // NBUCK*CAP uints
    uint* gmeta = glidx + (size_t)NBUCK * CAP;               // NBUCK*128
    int* bcurA  = (int*)(gmeta + (size_t)NBUCK * 128);       // NBUCK
    int* bcurB  = bcurA + NBUCK;
    ushort* Wpack = (ushort*)(((size_t)(bcurB + NBUCK) + 63) & ~(size_t)63);

    const int* srcA = ei_a;
    const int* dstA = ei_a + NE;
    const int* srcB = ei_b;
    const int* dstB = ei_b + NE;

    hipMemsetAsync(bcurA, 0, 2ull * NBUCK * sizeof(int), stream);
    build_kernel<<<2 * PBLK + F2B_BLKS + WPREP_BLKS, 256, 0, stream>>>(
        (const float4*)x, (uint2*)featb, (uint*)feat8, Wl, Wr, Wpack,
        srcA, dstA, srcB, dstB, bcurA, bcurB, ebufA, ebufB);

    fused_kernel<<<NBUCK, 1024, 0, stream>>>(
        (const uint4*)featb, (const uint4*)feat8, ebufA, ebufB, bcurA, bcurB,
        glidx, gmeta, Wpack, bl + 0 * D, bl + 1 * D,
        nullptr, feat2, feat28, 1, 0);
    fused_kernel<<<NBUCK, 1024, 0, stream>>>(
        (const uint4*)feat2, (const uint4*)feat28, ebufA, ebufB, bcurA, bcurB,
        glidx, gmeta, Wpack + (size_t)12 * 128 * 32, bl + 2 * D, bl + 3 * D,
        out, nullptr, nullptr, 0, 1);
}